// Round 18
// baseline (100.071 us; speedup 1.0000x reference)
//
#include <hip/hip_runtime.h>

#define LN_EPS 1e-5f

typedef __attribute__((ext_vector_type(8)))  short short8;
typedef __attribute__((ext_vector_type(4)))  float floatx4;

__device__ __forceinline__ unsigned short f2bf(float x) {
    unsigned u = __float_as_uint(x);
    u += 0x7FFFu + ((u >> 16) & 1u);   // round-to-nearest-even
    return (unsigned short)(u >> 16);
}

// ---------------------------------------------------------------------------
// Kernel A (fused): blocks [0, nEB): per-edge MLP coords -> h B-frags (16x16),
//   counts (atomic) and rank[e].  blocks [nEB, nEB+16): W2 -> bf16 A-frags.
// 16x16x32 frag convention (m89-verified; passed in rounds 3/4/15):
//   B-frag (16-edge tile et): lane l holds e = et*16+(l&15), k = (l>>4)*8+b.
//     short8 idx = et*64 + (e&15) + 16*(k>>3).
//   A-frag (j-tile jt): lane l holds j = jt*16+(l&15), k = (l>>4)*8+b.
//     short8 idx = jt*64 + l.
// ---------------------------------------------------------------------------
__global__ __launch_bounds__(256) void k_edge_mlp(
    const float* __restrict__ coords,
    const int*   __restrict__ target,
    const float* __restrict__ W0, const float* __restrict__ b0,
    const float* __restrict__ g0, const float* __restrict__ be0,
    const float* __restrict__ W1, const float* __restrict__ b1,
    const float* __restrict__ g1, const float* __restrict__ be1,
    const float* __restrict__ W2, unsigned short* __restrict__ w2frag,
    unsigned short* __restrict__ hfrag, int* __restrict__ counts,
    int* __restrict__ rank, int E, int nEB)
{
    const int tid = threadIdx.x;

    if (blockIdx.x >= nEB) {            // ---- W2 converter blocks ----
        const int idx = (blockIdx.x - nEB) * 256 + tid;   // 0..4095
        if (idx < 4096) {
            const int l  = idx & 63;
            const int jt = idx >> 6;          // 0..63
            const int j  = jt*16 + (l & 15);
            const int kb = (l >> 4) * 8;
            short8 v;
            #pragma unroll
            for (int b = 0; b < 8; ++b)
                v[b] = (short)f2bf(W2[(size_t)(kb + b)*1024 + j]);
            ((short8*)w2frag)[idx] = v;
        }
        return;
    }

    __shared__ float sW0[3*32], sW1T[32*36];   // W1T[o][c], stride 36
    __shared__ float sb0[32], sg0[32], sbe0[32], sb1[32], sg1[32], sbe1[32];
    for (int i = tid; i < 32*32; i += 256) {
        const int o = i & 31, c = i >> 5;
        sW1T[o*36 + c] = W1[i];                // W1[c*32+o]
    }
    if (tid < 96) sW0[tid] = W0[tid];
    if (tid < 32) {
        sb0[tid] = b0[tid];  sg0[tid] = g0[tid];  sbe0[tid] = be0[tid];
        sb1[tid] = b1[tid];  sg1[tid] = g1[tid];  sbe1[tid] = be1[tid];
    }
    __syncthreads();

    const int e = blockIdx.x * 256 + tid;
    if (e >= E) return;

    const float x0 = coords[e*3+0];
    const float x1 = coords[e*3+1];
    const float x2 = coords[e*3+2];

    float h[32];
    #pragma unroll
    for (int o = 0; o < 32; ++o)
        h[o] = x0*sW0[o] + x1*sW0[32+o] + x2*sW0[64+o] + sb0[o];

    {
        float mu = 0.f;
        #pragma unroll
        for (int o = 0; o < 32; ++o) mu += h[o];
        mu *= (1.f/32.f);
        float var = 0.f;
        #pragma unroll
        for (int o = 0; o < 32; ++o) { float d = h[o]-mu; var += d*d; }
        var *= (1.f/32.f);
        const float inv = rsqrtf(var + LN_EPS);
        #pragma unroll
        for (int o = 0; o < 32; ++o)
            h[o] = fmaxf((h[o]-mu)*inv*sg0[o] + sbe0[o], 0.f);
    }

    float h2[32];
    #pragma unroll
    for (int o = 0; o < 32; ++o) {
        float s = sb1[o];
        #pragma unroll
        for (int c4 = 0; c4 < 8; ++c4) {
            const floatx4 wv = *reinterpret_cast<const floatx4*>(&sW1T[o*36 + c4*4]);
            s += h[c4*4+0]*wv[0] + h[c4*4+1]*wv[1]
               + h[c4*4+2]*wv[2] + h[c4*4+3]*wv[3];
        }
        h2[o] = s;
    }

    {
        float mu = 0.f;
        #pragma unroll
        for (int o = 0; o < 32; ++o) mu += h2[o];
        mu *= (1.f/32.f);
        float var = 0.f;
        #pragma unroll
        for (int o = 0; o < 32; ++o) { float d = h2[o]-mu; var += d*d; }
        var *= (1.f/32.f);
        const float inv = rsqrtf(var + LN_EPS);
        #pragma unroll
        for (int o = 0; o < 32; ++o)
            h2[o] = fmaxf((h2[o]-mu)*inv*sg1[o] + sbe1[o], 0.f);
    }

    // 16x16 B-frag store (round-3 layout, proven)
    const int et = e >> 4, er = e & 15;
    short8* base = (short8*)(hfrag) + (size_t)et * 64;
    #pragma unroll
    for (int kg = 0; kg < 4; ++kg) {
        short8 v;
        #pragma unroll
        for (int b = 0; b < 8; ++b) v[b] = (short)f2bf(h2[kg*8 + b]);
        base[er + 16*kg] = v;
    }

    rank[e] = atomicAdd(&counts[target[e]], 1);
}

// ---------------------------------------------------------------------------
// Kernel scan: exclusive prefix sum of counts[N] -> offs[N+1]. (Round-17
// coalesced-LDS version — kept.)
// ---------------------------------------------------------------------------
__global__ __launch_bounds__(1024) void k_scan(
    const int* __restrict__ counts, int* __restrict__ offs, int N)
{
    __shared__ int sC[10240];
    __shared__ int wsum[16];
    const int t = threadIdx.x;
    const int lane = t & 63, w = t >> 6;
    const int CH = (N + 1023) >> 10;

    for (int i = t; i < N; i += 1024) sC[i] = counts[i];    // coalesced in
    __syncthreads();

    const int beg = t * CH;
    int s = 0;
    #pragma unroll 4
    for (int k = 0; k < CH; ++k) {
        const int i = beg + k;
        if (i < N) s += sC[i];
    }
    int incl = s;
    #pragma unroll
    for (int d = 1; d < 64; d <<= 1) {
        const int x = __shfl_up(incl, d);
        if (lane >= d) incl += x;
    }
    if (lane == 63) wsum[w] = incl;
    __syncthreads();
    if (t == 0) {
        int run = 0;
        #pragma unroll
        for (int i = 0; i < 16; ++i) { const int v = wsum[i]; wsum[i] = run; run += v; }
    }
    __syncthreads();
    const int base = wsum[w] + incl - s;
    int run = base;
    #pragma unroll 4
    for (int k = 0; k < CH; ++k) {
        const int i = beg + k;
        if (i < N) { const int c = sC[i]; sC[i] = run; run += c; }
    }
    __syncthreads();
    for (int i = t; i < N; i += 1024) offs[i] = sC[i];      // coalesced out
    if (t == 1023) offs[N] = base + s;
}

// ---------------------------------------------------------------------------
// Kernel B: 16x16x32 MFMA, D[j,e] = W2T_jt @ h_et16, SAME 32-edge x 512-col
// unit as round 10 (2 blocks/tile via jh).  256 thr = 4 waves; wave W owns
// o = W*4..W*4+3 (j = W*128..W*128+127 = 8 j-tiles), edges split as 2
// 16-edge B-frags (lo/hi).
// WHY (round-18): occupancy is set by VGPR+AGPR TOTAL (unified file; m69
// brackets at 64/128/256; rocprof VGPR_Count excludes AGPR). The 32x32
// version holds 4 floatx16 accumulators (64+ AGPR) -> total >128 -> 2
// waves/SIMD (26% occ, rounds 10-17). floatx4 accumulators cut that to
// <=16 AGPR -> total ~100 -> 4 waves/SIMD bracket.
// Epilogue identical: t = fma(d, KE, KE*b2) [LDS]; r = rcp(exp2(t)+1);
//   oc[e,o] = fsum - 2*sum(f*r). sOC staging + 1 barrier/unit (round 10).
// ---------------------------------------------------------------------------
__global__ __launch_bounds__(256, 2) void k_field_mfma(
    const unsigned short* __restrict__ hfrag,
    const unsigned short* __restrict__ w2frag,
    const float* __restrict__ features,
    const int*   __restrict__ src,
    const int*   __restrict__ tgt,
    const int*   __restrict__ rank,
    const int*   __restrict__ offs,
    const float* __restrict__ b2,
    unsigned short* __restrict__ ocP,
    int netiles)                        // 32-edge tiles
{
    __shared__ float s_b2s[1024];
    __shared__ unsigned int sOC[2][32*9];   // 32 rows x 8 dwords, stride 9
    __shared__ int sP[2][32];
    const int tid = threadIdx.x;
    const float KE = 2.8853900817779268f;   // 2*log2(e)
    #pragma unroll
    for (int r = 0; r < 4; ++r) s_b2s[tid + 256*r] = KE * b2[tid + 256*r];

    const int lane = tid & 63;
    const int wq   = tid >> 6;              // 0..3 wave in block
    const int jh   = blockIdx.x & 1;        // j-half (gridDim EVEN)
    const int W    = jh*4 + wq;             // 0..7 o-block (o = W*4+u)
    const int g    = lane >> 4;             // 0..3 row group
    const int el   = lane & 15;             // e within 16-edge tile
    const int str  = tid >> 3;              // store-pass row 0..31
    const int sti  = tid & 7;               // store-pass dword 0..7

    // resident W2 A-frags: 8 x short8 = 32 VGPR (j-tiles W*8 .. W*8+7)
    short8 afr[8];
    #pragma unroll
    for (int u2 = 0; u2 < 8; ++u2)
        afr[u2] = ((const short8*)w2frag)[(W*8 + u2)*64 + lane];
    __syncthreads();

    const floatx4 z4 = {0.f, 0.f, 0.f, 0.f};
    const int nunits = 2*netiles;
    int buf = 0;
    for (int unit = blockIdx.x; unit < nunits; unit += gridDim.x, buf ^= 1) {
        const int et32 = unit >> 1;
        const int e0   = et32 << 5;
        const short8 bs_lo = ((const short8*)hfrag)[(et32*2    )*64 + lane];
        const short8 bs_hi = ((const short8*)hfrag)[(et32*2 + 1)*64 + lane];

        const int sNl = src[e0 + el];
        const int sNh = src[e0 + 16 + el];
        if (tid < 32) sP[buf][tid] = offs[tgt[e0 + tid]] + rank[e0 + tid];

        // f gathers: lane needs i = h2*16 + g*4 + r for its two edges
        const floatx4 fl0 = *reinterpret_cast<const floatx4*>(features + (size_t)sNl*32 + g*4);
        const floatx4 fl1 = *reinterpret_cast<const floatx4*>(features + (size_t)sNl*32 + 16 + g*4);
        const floatx4 fh0 = *reinterpret_cast<const floatx4*>(features + (size_t)sNh*32 + g*4);
        const floatx4 fh1 = *reinterpret_cast<const floatx4*>(features + (size_t)sNh*32 + 16 + g*4);

        float fsl = ((fl0[0]+fl0[1]) + (fl0[2]+fl0[3]))
                  + ((fl1[0]+fl1[1]) + (fl1[2]+fl1[3]));
        fsl += __shfl_xor(fsl, 16);
        fsl += __shfl_xor(fsl, 32);      // full fsum for edge e0+el
        float fsh = ((fh0[0]+fh0[1]) + (fh0[2]+fh0[3]))
                  + ((fh1[0]+fh1[1]) + (fh1[2]+fh1[3]));
        fsh += __shfl_xor(fsh, 16);
        fsh += __shfl_xor(fsh, 32);      // full fsum for edge e0+16+el

        float ql[4], qh[4];
        #pragma unroll
        for (int u = 0; u < 4; ++u) {
            float sl = 0.f, sh = 0.f;
            #pragma unroll
            for (int h2 = 0; h2 < 2; ++h2) {
                const int u2 = u*2 + h2;
                const floatx4 dl = __builtin_amdgcn_mfma_f32_16x16x32_bf16(afr[u2], bs_lo, z4, 0, 0, 0);
                const floatx4 dh = __builtin_amdgcn_mfma_f32_16x16x32_bf16(afr[u2], bs_hi, z4, 0, 0, 0);
                const floatx4 bq = *reinterpret_cast<const floatx4*>(&s_b2s[W*128 + u2*16 + g*4]);
                const floatx4 fl = h2 ? fl1 : fl0;
                const floatx4 fh = h2 ? fh1 : fh0;
                #pragma unroll
                for (int r = 0; r < 4; ++r) {
                    const float t0 = fmaf(dl[r], KE, bq[r]);
                    sl = fmaf(fl[r], __builtin_amdgcn_rcpf(__builtin_amdgcn_exp2f(t0) + 1.0f), sl);
                    const float t1 = fmaf(dh[r], KE, bq[r]);
                    sh = fmaf(fh[r], __builtin_amdgcn_rcpf(__builtin_amdgcn_exp2f(t1) + 1.0f), sh);
                }
            }
            float vl = -2.0f * sl;
            vl += __shfl_xor(vl, 16);
            vl += __shfl_xor(vl, 32);
            ql[u] = vl + fsl;
            float vh = -2.0f * sh;
            vh += __shfl_xor(vh, 16);
            vh += __shfl_xor(vh, 32);
            qh[u] = vh + fsh;
        }

        if (lane < 16) {
            sOC[buf][el*9 + wq*2]     = ((unsigned)f2bf(ql[1]) << 16) | f2bf(ql[0]);
            sOC[buf][el*9 + wq*2 + 1] = ((unsigned)f2bf(ql[3]) << 16) | f2bf(ql[2]);
        } else if (lane < 32) {
            sOC[buf][(16+el)*9 + wq*2]     = ((unsigned)f2bf(qh[1]) << 16) | f2bf(qh[0]);
            sOC[buf][(16+el)*9 + wq*2 + 1] = ((unsigned)f2bf(qh[3]) << 16) | f2bf(qh[2]);
        }
        __syncthreads();
        // store pass: 8 lanes/row -> one contiguous 32B store per row-half
        ((unsigned int*)ocP)[(size_t)sP[buf][str]*16 + jh*8 + sti] = sOC[buf][str*9 + sti];
        // no trailing barrier: double-buffered; this buf re-written only
        // after the NEXT iteration's barrier.
    }
}

// ---------------------------------------------------------------------------
// Kernel gather: CSR rows of ocP (target-sorted), mean, write out.
// ---------------------------------------------------------------------------
__global__ __launch_bounds__(256) void k_gather(
    const unsigned short* __restrict__ ocP,
    const int* __restrict__ offs,
    float* __restrict__ out, int N)
{
    const int node = blockIdx.x * 4 + (threadIdx.x >> 6);
    const int lane = threadIdx.x & 63;
    if (node >= N) return;
    const int r = lane >> 3;        // 0..7  row stagger
    const int c = lane & 7;         // 0..7  o-chunk (4 shorts)
    const int beg = offs[node], end = offs[node + 1];

    float a0 = 0.f, a1 = 0.f, a2 = 0.f, a3 = 0.f;
    for (int k = beg + r; k < end; k += 8) {
        const uint2 v = *reinterpret_cast<const uint2*>(ocP + (size_t)k*32 + c*4);
        a0 += __uint_as_float(v.x << 16);
        a1 += __uint_as_float(v.x & 0xFFFF0000u);
        a2 += __uint_as_float(v.y << 16);
        a3 += __uint_as_float(v.y & 0xFFFF0000u);
    }
    #pragma unroll
    for (int m = 8; m < 64; m <<= 1) {
        a0 += __shfl_xor(a0, m);
        a1 += __shfl_xor(a1, m);
        a2 += __shfl_xor(a2, m);
        a3 += __shfl_xor(a3, m);
    }
    if (lane < 8) {
        const float rinv = __builtin_amdgcn_rcpf(fmaxf((float)(end - beg), 1.0f));
        floatx4 o4 = {a0*rinv, a1*rinv, a2*rinv, a3*rinv};
        *reinterpret_cast<floatx4*>(out + (size_t)node*32 + lane*4) = o4;
    }
}

// ---------------------------------------------------------------------------
extern "C" void kernel_launch(void* const* d_in, const int* in_sizes, int n_in,
                              void* d_out, int out_size, void* d_ws, size_t ws_size,
                              hipStream_t stream)
{
    const float* features = (const float*)d_in[0];
    const float* coords   = (const float*)d_in[1];
    const int*   src      = (const int*)  d_in[2];
    const int*   tgt      = (const int*)  d_in[3];
    const float* W0  = (const float*)d_in[4];
    const float* b0  = (const float*)d_in[5];
    const float* g0  = (const float*)d_in[6];
    const float* be0 = (const float*)d_in[7];
    const float* W1  = (const float*)d_in[8];
    const float* b1  = (const float*)d_in[9];
    const float* g1  = (const float*)d_in[10];
    const float* be1 = (const float*)d_in[11];
    const float* W2  = (const float*)d_in[12];
    const float* b2  = (const float*)d_in[13];

    const int E = in_sizes[2];           // 160000 (multiple of 32)
    const int N = in_sizes[0] / 32;      // 10000

    char* p = (char*)d_ws;
    unsigned short* hfrag  = (unsigned short*)p;  p += (size_t)E*32*2;   // 10.24 MB
    unsigned short* ocP    = (unsigned short*)p;  p += (size_t)E*32*2;   // 10.24 MB
    unsigned short* w2frag = (unsigned short*)p;  p += 32*1024*2;        // 64 KB
    int* rankArr = (int*)p;  p += (size_t)E*4;                           // 640 KB
    int* counts  = (int*)p;  p += (size_t)N*4;
    int* offs    = (int*)p;  p += (size_t)(N+1)*4;

    (void)hipMemsetAsync(counts, 0, (size_t)N*4, stream);

    const int nEB = (E + 255)/256;       // 625 edge blocks + 16 w2 blocks
    k_edge_mlp<<<nEB + 16, 256, 0, stream>>>(
        coords, tgt, W0, b0, g0, be0, W1, b1, g1, be1, W2, w2frag,
        hfrag, counts, rankArr, E, nEB);

    k_scan<<<1, 1024, 0, stream>>>(counts, offs, N);

    const int netiles = E / 32;          // 5000 -> nunits 10000
    k_field_mfma<<<2048, 256, 0, stream>>>(
        hfrag, w2frag, features, src, tgt, rankArr, offs, b2, ocP, netiles);

    k_gather<<<(N + 3)/4, 256, 0, stream>>>(ocP, offs, (float*)d_out, N);
}